// Round 1
// baseline (125.866 us; speedup 1.0000x reference)
//
#include <hip/hip_runtime.h>
#include <hip/hip_bf16.h>
#include <math.h>

// Problem constants (from reference)
#define NNODE 120000
#define DDIM  128
#define SS    100
#define NNEGS 50
#define ROWS_A 1600    // anchor/positive rows per type: 4 slices x 4 idsets x 100
#define ROWS_N 20000   // cross-neg rows per type: 4 slices x 100 x 50
#define TOTAL_ROWS 43200
#define ROWS_PB 32
#define INV_TEMP 2.0f

// ws row layout (each row = 128 floats of normalized projection):
//   [0,1600)       A_p  : slice(4) x idset(4) x s(100)   (emb_p rows at idx_p)
//   [1600,3200)    A_c  : same, emb_c rows at idx_c
//   [3200,23200)   N_pc : vl(4) x s(100) x n(50)         (emb_c rows at neg_idx_p)
//   [23200,43200)  N_cp : emb_p rows at neg_idx_c

__device__ __forceinline__ bool idx_is64(const void* p) {
  // int64 little-endian non-negative small values => odd 32-bit words are 0.
  // int32 random indices in [0,120000): odd words are other values, ~never all 0.
  const unsigned* q = (const unsigned*)p;
  return (q[1] | q[3] | q[5] | q[7]) == 0u;
}

__device__ __forceinline__ int ld_idx(const void* p, int i, bool is64) {
  return is64 ? (int)((const long long*)p)[i] : ((const int*)p)[i];
}

__global__ __launch_bounds__(128)
void proj_kernel(const float* __restrict__ emb_p, const float* __restrict__ emb_c,
                 const float* __restrict__ W1, const float* __restrict__ b1,
                 const float* __restrict__ W2, const float* __restrict__ b2,
                 const void* __restrict__ idx_p, const void* __restrict__ idx_c,
                 const void* __restrict__ nidx_p, const void* __restrict__ nidx_c,
                 float* __restrict__ ws)
{
  __shared__ __align__(16) float xs[ROWS_PB][DDIM];
  __shared__ __align__(16) float hs[ROWS_PB][DDIM];
  const int t = threadIdx.x;
  const bool is64 = idx_is64(idx_p);
  const int base = blockIdx.x * ROWS_PB;

  // ---- gather 32 rows (coalesced: thread t loads element t of each row) ----
  for (int r = 0; r < ROWS_PB; ++r) {
    const int rid = base + r;
    const float* src;
    if (rid < 2 * ROWS_A) {
      const int typ = rid / ROWS_A;          // 0: p anchors, 1: c anchors
      const int rr  = rid - typ * ROWS_A;
      const int slice = rr / 400;            // v*2+l of the Pz slice
      const int rem   = rr - slice * 400;    // g*100 + s  (g = idset)
      const int node  = ld_idx(typ ? idx_c : idx_p, rem, is64);
      const float* emb = typ ? emb_c : emb_p;
      src = emb + ((size_t)slice * NNODE + node) * DDIM;
    } else {
      const int r2  = rid - 2 * ROWS_A;
      const int typ = r2 / ROWS_N;           // 0: N_pc (neg_idx_p -> emb_c), 1: N_cp
      const int rr  = r2 - typ * ROWS_N;
      const int slice = rr / (SS * NNEGS);
      const int rem   = rr - slice * (SS * NNEGS);   // s*50+n
      const int node  = ld_idx(typ ? nidx_c : nidx_p, slice * (SS * NNEGS) + rem, is64);
      const float* emb = typ ? emb_p : emb_c;
      src = emb + ((size_t)slice * NNODE + node) * DDIM;
    }
    xs[r][t] = src[t];
  }
  __syncthreads();

  // ---- thread tile: 8 rows x 4 cols ----
  const int j0 = 4 * (t & 31);     // output columns j0..j0+3
  const int r0 = 8 * (t >> 5);     // rows r0..r0+7
  float acc[8][4];

  // layer 1: H = relu(X @ W1 + b1)
  {
    const float4 bv = *(const float4*)(b1 + j0);
    #pragma unroll
    for (int r = 0; r < 8; ++r) { acc[r][0]=bv.x; acc[r][1]=bv.y; acc[r][2]=bv.z; acc[r][3]=bv.w; }
    for (int d4 = 0; d4 < DDIM / 4; ++d4) {
      const float4 wa = *(const float4*)(W1 + (size_t)(d4*4+0)*DDIM + j0);
      const float4 wb = *(const float4*)(W1 + (size_t)(d4*4+1)*DDIM + j0);
      const float4 wc = *(const float4*)(W1 + (size_t)(d4*4+2)*DDIM + j0);
      const float4 wd = *(const float4*)(W1 + (size_t)(d4*4+3)*DDIM + j0);
      #pragma unroll
      for (int r = 0; r < 8; ++r) {
        const float4 xv = *(const float4*)(&xs[r0 + r][d4 * 4]);
        acc[r][0] = fmaf(xv.x, wa.x, acc[r][0]); acc[r][0] = fmaf(xv.y, wb.x, acc[r][0]);
        acc[r][0] = fmaf(xv.z, wc.x, acc[r][0]); acc[r][0] = fmaf(xv.w, wd.x, acc[r][0]);
        acc[r][1] = fmaf(xv.x, wa.y, acc[r][1]); acc[r][1] = fmaf(xv.y, wb.y, acc[r][1]);
        acc[r][1] = fmaf(xv.z, wc.y, acc[r][1]); acc[r][1] = fmaf(xv.w, wd.y, acc[r][1]);
        acc[r][2] = fmaf(xv.x, wa.z, acc[r][2]); acc[r][2] = fmaf(xv.y, wb.z, acc[r][2]);
        acc[r][2] = fmaf(xv.z, wc.z, acc[r][2]); acc[r][2] = fmaf(xv.w, wd.z, acc[r][2]);
        acc[r][3] = fmaf(xv.x, wa.w, acc[r][3]); acc[r][3] = fmaf(xv.y, wb.w, acc[r][3]);
        acc[r][3] = fmaf(xv.z, wc.w, acc[r][3]); acc[r][3] = fmaf(xv.w, wd.w, acc[r][3]);
      }
    }
    #pragma unroll
    for (int r = 0; r < 8; ++r) {
      *(float4*)(&hs[r0 + r][j0]) = make_float4(
          fmaxf(acc[r][0], 0.f), fmaxf(acc[r][1], 0.f),
          fmaxf(acc[r][2], 0.f), fmaxf(acc[r][3], 0.f));
    }
  }
  __syncthreads();

  // layer 2: Z = H @ W2 + b2
  {
    const float4 bv = *(const float4*)(b2 + j0);
    #pragma unroll
    for (int r = 0; r < 8; ++r) { acc[r][0]=bv.x; acc[r][1]=bv.y; acc[r][2]=bv.z; acc[r][3]=bv.w; }
    for (int d4 = 0; d4 < DDIM / 4; ++d4) {
      const float4 wa = *(const float4*)(W2 + (size_t)(d4*4+0)*DDIM + j0);
      const float4 wb = *(const float4*)(W2 + (size_t)(d4*4+1)*DDIM + j0);
      const float4 wc = *(const float4*)(W2 + (size_t)(d4*4+2)*DDIM + j0);
      const float4 wd = *(const float4*)(W2 + (size_t)(d4*4+3)*DDIM + j0);
      #pragma unroll
      for (int r = 0; r < 8; ++r) {
        const float4 xv = *(const float4*)(&hs[r0 + r][d4 * 4]);
        acc[r][0] = fmaf(xv.x, wa.x, acc[r][0]); acc[r][0] = fmaf(xv.y, wb.x, acc[r][0]);
        acc[r][0] = fmaf(xv.z, wc.x, acc[r][0]); acc[r][0] = fmaf(xv.w, wd.x, acc[r][0]);
        acc[r][1] = fmaf(xv.x, wa.y, acc[r][1]); acc[r][1] = fmaf(xv.y, wb.y, acc[r][1]);
        acc[r][1] = fmaf(xv.z, wc.y, acc[r][1]); acc[r][1] = fmaf(xv.w, wd.y, acc[r][1]);
        acc[r][2] = fmaf(xv.x, wa.z, acc[r][2]); acc[r][2] = fmaf(xv.y, wb.z, acc[r][2]);
        acc[r][2] = fmaf(xv.z, wc.z, acc[r][2]); acc[r][2] = fmaf(xv.w, wd.z, acc[r][2]);
        acc[r][3] = fmaf(xv.x, wa.w, acc[r][3]); acc[r][3] = fmaf(xv.y, wb.w, acc[r][3]);
        acc[r][3] = fmaf(xv.z, wc.w, acc[r][3]); acc[r][3] = fmaf(xv.w, wd.w, acc[r][3]);
      }
    }
  }
  // write Z back into xs (different buffer than hs being read; safe pre-sync)
  #pragma unroll
  for (int r = 0; r < 8; ++r)
    *(float4*)(&xs[r0 + r][j0]) = make_float4(acc[r][0], acc[r][1], acc[r][2], acc[r][3]);
  __syncthreads();

  // ---- L2 normalize + store (each wave handles 16 rows) ----
  const int wave = t >> 6, lane = t & 63;
  for (int rr = 0; rr < ROWS_PB / 2; ++rr) {
    const int r = wave * (ROWS_PB / 2) + rr;
    const float a0 = xs[r][lane], a1 = xs[r][lane + 64];
    float ssq = a0 * a0 + a1 * a1;
    #pragma unroll
    for (int m = 1; m < 64; m <<= 1) ssq += __shfl_xor(ssq, m);
    const float sc = 1.0f / fmaxf(sqrtf(ssq), 1e-12f);
    const size_t o = (size_t)(base + r) * DDIM;
    ws[o + lane]      = a0 * sc;
    ws[o + lane + 64] = a1 * sc;
  }
}

__global__ __launch_bounds__(256)
void loss_kernel(const float* __restrict__ ws, float* __restrict__ out)
{
  const int bid = blockIdx.x;            // 0..799 = type(2) x vl(4) x s(100)
  const int typ = bid / 400;
  const int rem = bid - typ * 400;
  const int vl  = rem / SS;              // vi*2+li
  const int s   = rem - vl * SS;
  const float* A  = ws + (size_t)(typ ? ROWS_A : 0) * DDIM;
  const float* Nb = ws + (size_t)(2 * ROWS_A + (typ ? ROWS_N : 0)) * DDIM;
  const float* zs = A + (size_t)((vl * 4 + vl) * SS + s) * DDIM;  // slice=vl, idset=vl

  const int lane = threadIdx.x & 63;
  const int wave = threadIdx.x >> 6;
  const float z0 = zs[lane], z1 = zs[lane + 64];
  float pos_acc = 0.f, neg_acc = 0.f;

  // targets: [0,3) positives (other 3 slices, same idset & s)
  //          [3,102) within-negatives (t != s in same slice/idset)
  //          [102,152) cross-negatives
  for (int tgt = wave; tgt < 152; tgt += 4) {
    const float* tp;
    bool is_pos = false;
    if (tgt < 3) {
      const int k = tgt + (tgt >= vl ? 1 : 0);          // slice != vl
      tp = A + (size_t)((k * 4 + vl) * SS + s) * DDIM;
      is_pos = true;
    } else if (tgt < 102) {
      int t2 = tgt - 3;
      if (t2 >= s) ++t2;                                 // skip self
      tp = A + (size_t)((vl * 4 + vl) * SS + t2) * DDIM;
    } else {
      const int n = tgt - 102;
      tp = Nb + (size_t)((vl * SS + s) * NNEGS + n) * DDIM;
    }
    float d = z0 * tp[lane] + z1 * tp[lane + 64];
    #pragma unroll
    for (int m = 1; m < 64; m <<= 1) d += __shfl_xor(d, m);
    const float e = expf(d * INV_TEMP);
    if (is_pos) pos_acc += e; else neg_acc += e;
  }

  __shared__ float sp[4], sn[4];
  if (lane == 0) { sp[wave] = pos_acc; sn[wave] = neg_acc; }
  __syncthreads();
  if (threadIdx.x == 0) {
    const float P  = sp[0] + sp[1] + sp[2] + sp[3];
    const float Ng = sn[0] + sn[1] + sn[2] + sn[3];
    atomicAdd(out, -logf(P / (P + Ng)) * (1.0f / 800.0f));
  }
}

extern "C" void kernel_launch(void* const* d_in, const int* in_sizes, int n_in,
                              void* d_out, int out_size, void* d_ws, size_t ws_size,
                              hipStream_t stream) {
  const float* emb_p = (const float*)d_in[0];
  const float* emb_c = (const float*)d_in[1];
  const float* W1    = (const float*)d_in[2];
  const float* b1    = (const float*)d_in[3];
  const float* W2    = (const float*)d_in[4];
  const float* b2    = (const float*)d_in[5];
  const void*  idx_p = d_in[6];
  const void*  idx_c = d_in[7];
  const void*  nidx_p = d_in[8];
  const void*  nidx_c = d_in[9];
  float* out = (float*)d_out;
  float* ws  = (float*)d_ws;

  hipMemsetAsync(out, 0, sizeof(float), stream);
  proj_kernel<<<TOTAL_ROWS / ROWS_PB, 128, 0, stream>>>(
      emb_p, emb_c, W1, b1, W2, b2, idx_p, idx_c, nidx_p, nidx_c, ws);
  loss_kernel<<<800, 256, 0, stream>>>(ws, out);
}

// Round 2
// 73.616 us; speedup vs baseline: 1.7098x; 1.7098x over previous
//
#include <hip/hip_runtime.h>
#include <math.h>

#define NNODE 120000
#define DDIM  128
#define SS    100
#define NNEGS 50
#define ROWS_A 1600    // anchor/positive rows per type: slice(4) x idset(4) x 100
#define ROWS_N 20000   // cross-neg rows per type: vl(4) x s(100) x n(50)
#define TOTAL_ROWS 43200
#define BLK_ROWS 64
#define ZROWS_BYTES (TOTAL_ROWS * DDIM * 2)   // 11,059,200 B, bf16 rows
#define WFRAG_SHORTS 16384                    // per layer: 4 kc x 8 ct x 64 lanes x 8
#define INV_TEMP 2.0f

typedef unsigned short ushort_t;
typedef __attribute__((ext_vector_type(8))) short bf16x8;
typedef __attribute__((ext_vector_type(4))) float f32x4;

__device__ __forceinline__ ushort_t f2b(float f) {
  unsigned u = __builtin_bit_cast(unsigned, f);
  u += 0x7fffu + ((u >> 16) & 1u);           // RNE
  return (ushort_t)(u >> 16);
}
__device__ __forceinline__ float b2f(ushort_t h) {
  return __builtin_bit_cast(float, (unsigned)h << 16);
}

__device__ __forceinline__ bool idx_is64(const void* p) {
  const unsigned* q = (const unsigned*)p;
  return (q[1] | q[3] | q[5] | q[7]) == 0u;
}
__device__ __forceinline__ int ld_idx(const void* p, int i, bool is64) {
  return is64 ? (int)((const long long*)p)[i] : ((const int*)p)[i];
}

// ws z-row layout (bf16 rows of 128):
//   [0,1600)       A_p : slice(4) x idset(4) x s(100)
//   [1600,3200)    A_c
//   [3200,23200)   N_pc : vl(4) x s(100) x n(50)   (emb_c at neg_idx_p)
//   [23200,43200)  N_cp
__device__ __forceinline__ const float* row_src(
    int rid, bool is64,
    const float* emb_p, const float* emb_c,
    const void* idx_p, const void* idx_c,
    const void* nidx_p, const void* nidx_c)
{
  if (rid < 2 * ROWS_A) {
    const int typ = rid / ROWS_A;
    const int rr  = rid - typ * ROWS_A;
    const int slice = rr / 400;
    const int rem   = rr - slice * 400;          // idset*100 + s
    const int node  = ld_idx(typ ? idx_c : idx_p, rem, is64);
    return (typ ? emb_c : emb_p) + ((size_t)slice * NNODE + node) * DDIM;
  } else {
    const int r2  = rid - 2 * ROWS_A;
    const int typ = r2 / ROWS_N;
    const int rr  = r2 - typ * ROWS_N;
    const int slice = rr / (SS * NNEGS);
    const int rem   = rr - slice * (SS * NNEGS);
    const int node  = ld_idx(typ ? nidx_c : nidx_p, slice * (SS * NNEGS) + rem, is64);
    return (typ ? emb_p : emb_c) + ((size_t)slice * NNODE + node) * DDIM;
  }
}

// Rearrange W1/W2 into B-fragment order (bf16).
// frag[layer][kc][ct][lane][e] = W[kc*32 + 8*(lane>>4) + e][ct*16 + (lane&15)]
__global__ __launch_bounds__(64)
void wfrag_kernel(const float* __restrict__ W1, const float* __restrict__ W2,
                  ushort_t* __restrict__ wfrag)
{
  const int b = blockIdx.x;                 // 64 = layer(2) x kc(4) x ct(8)
  const int layer = b >> 5, kc = (b >> 3) & 3, ct = b & 7;
  const int l = threadIdx.x;
  const float* W = layer ? W2 : W1;
  ushort_t* dst = wfrag + layer * WFRAG_SHORTS + (size_t)((kc * 8 + ct) * 64 + l) * 8;
  const int col   = ct * 16 + (l & 15);
  const int krow0 = kc * 32 + ((l >> 4) << 3);
  #pragma unroll
  for (int e = 0; e < 8; ++e)
    dst[e] = f2b(W[(size_t)(krow0 + e) * DDIM + col]);
}

__global__ __launch_bounds__(256)
void proj_kernel(const float* __restrict__ emb_p, const float* __restrict__ emb_c,
                 const float* __restrict__ b1v, const float* __restrict__ b2v,
                 const void* __restrict__ idx_p, const void* __restrict__ idx_c,
                 const void* __restrict__ nidx_p, const void* __restrict__ nidx_c,
                 const ushort_t* __restrict__ wfrag,
                 ushort_t* __restrict__ zout)
{
  __shared__ __align__(16) ushort_t xlds[BLK_ROWS][DDIM];  // wave-private 16-row slabs
  __shared__ __align__(16) ushort_t hlds[BLK_ROWS][DDIM];
  __shared__ __align__(16) ushort_t wlds[WFRAG_SHORTS];
  const int t = threadIdx.x, w = t >> 6, l = t & 63;
  const int g = l >> 4, li = l & 15;
  const bool is64 = idx_is64(idx_p);
  const int base = blockIdx.x * BLK_ROWS;
  const int r0 = w * 16;

  // stage W1 frags into LDS (cooperative, coalesced)
  {
    const uint4* s4 = (const uint4*)wfrag;
    uint4* d4 = (uint4*)wlds;
    #pragma unroll
    for (int i = 0; i < 8; ++i) d4[t + 256 * i] = s4[t + 256 * i];
  }
  // gather + bf16-convert this wave's 16 rows (full 512B row per wave instr)
  for (int rr = 0; rr < 16; ++rr) {
    const int r = r0 + rr;
    const float* src = row_src(base + r, is64, emb_p, emb_c, idx_p, idx_c, nidx_p, nidx_c);
    const float2 v = *(const float2*)(src + 2 * l);
    ushort2 hh; hh.x = f2b(v.x); hh.y = f2b(v.y);
    *(ushort2*)&xlds[r][2 * l] = hh;
  }
  __syncthreads();                                   // W1 + (own) X ready

  f32x4 acc[8];
  // ---- layer 1: H = relu(X @ W1 + b1) ----
  #pragma unroll
  for (int ct = 0; ct < 8; ++ct) {
    const float bv = b1v[ct * 16 + li];
    acc[ct] = (f32x4){bv, bv, bv, bv};
  }
  #pragma unroll
  for (int kc = 0; kc < 4; ++kc) {
    const bf16x8 av = *(const bf16x8*)&xlds[r0 + li][kc * 32 + g * 8];
    #pragma unroll
    for (int ct = 0; ct < 8; ++ct) {
      const bf16x8 bfr = *(const bf16x8*)&wlds[(size_t)((kc * 8 + ct) * 64 + l) * 8];
      acc[ct] = __builtin_amdgcn_mfma_f32_16x16x32_bf16(av, bfr, acc[ct], 0, 0, 0);
    }
  }
  // relu + bf16 H into own rows (D: row = 4*g+reg, col = ct*16+li)
  #pragma unroll
  for (int ct = 0; ct < 8; ++ct)
    #pragma unroll
    for (int rg = 0; rg < 4; ++rg)
      hlds[r0 + 4 * g + rg][ct * 16 + li] = f2b(fmaxf(acc[ct][rg], 0.f));
  __syncthreads();                                   // all W1 reads done
  // stage W2 frags
  {
    const uint4* s4 = (const uint4*)(wfrag + WFRAG_SHORTS);
    uint4* d4 = (uint4*)wlds;
    #pragma unroll
    for (int i = 0; i < 8; ++i) d4[t + 256 * i] = s4[t + 256 * i];
  }
  __syncthreads();                                   // W2 ready

  // ---- layer 2: Z = H @ W2 + b2 ----
  #pragma unroll
  for (int ct = 0; ct < 8; ++ct) {
    const float bv = b2v[ct * 16 + li];
    acc[ct] = (f32x4){bv, bv, bv, bv};
  }
  #pragma unroll
  for (int kc = 0; kc < 4; ++kc) {
    const bf16x8 av = *(const bf16x8*)&hlds[r0 + li][kc * 32 + g * 8];
    #pragma unroll
    for (int ct = 0; ct < 8; ++ct) {
      const bf16x8 bfr = *(const bf16x8*)&wlds[(size_t)((kc * 8 + ct) * 64 + l) * 8];
      acc[ct] = __builtin_amdgcn_mfma_f32_16x16x32_bf16(av, bfr, acc[ct], 0, 0, 0);
    }
  }
  // ---- L2 norm (reduce across the 16 lanes holding each row) ----
  float sc[4];
  #pragma unroll
  for (int rg = 0; rg < 4; ++rg) {
    float ssq = 0.f;
    #pragma unroll
    for (int ct = 0; ct < 8; ++ct) ssq += acc[ct][rg] * acc[ct][rg];
    ssq += __shfl_xor(ssq, 1);
    ssq += __shfl_xor(ssq, 2);
    ssq += __shfl_xor(ssq, 4);
    ssq += __shfl_xor(ssq, 8);
    sc[rg] = 1.f / fmaxf(sqrtf(ssq), 1e-12f);
  }
  // stage normalized Z (bf16) into xlds (own rows; xlds is dead now)
  #pragma unroll
  for (int ct = 0; ct < 8; ++ct)
    #pragma unroll
    for (int rg = 0; rg < 4; ++rg)
      xlds[r0 + 4 * g + rg][ct * 16 + li] = f2b(acc[ct][rg] * sc[rg]);
  __syncthreads();                                   // Z staged block-wide
  // coalesced 16 KB copy-out
  {
    const uint4* s4 = (const uint4*)xlds;
    uint4* d4 = (uint4*)zout + (size_t)base * 16;    // base*256 B
    #pragma unroll
    for (int i = 0; i < 4; ++i) d4[t + 256 * i] = s4[t + 256 * i];
  }
}

__global__ __launch_bounds__(256)
void loss_kernel(const ushort_t* __restrict__ zb, float* __restrict__ out)
{
  const int bid = blockIdx.x;            // type(2) x vl(4) x s(100)
  const int typ = bid / 400;
  const int rem = bid - typ * 400;
  const int vl  = rem / SS;
  const int s   = rem - vl * SS;
  const ushort_t* A  = zb + (size_t)(typ ? ROWS_A : 0) * DDIM;
  const ushort_t* Nb = zb + (size_t)(2 * ROWS_A + (typ ? ROWS_N : 0)) * DDIM;
  const ushort_t* zs = A + (size_t)((vl * 4 + vl) * SS + s) * DDIM;

  const int lane = threadIdx.x & 63;
  const int wave = threadIdx.x >> 6;
  const ushort2 zz = *(const ushort2*)(zs + 2 * lane);
  const float z0 = b2f(zz.x), z1 = b2f(zz.y);
  float pos_acc = 0.f, neg_acc = 0.f;

  for (int tgt = wave; tgt < 152; tgt += 4) {
    const ushort_t* tp;
    bool is_pos = false;
    if (tgt < 3) {
      const int k = tgt + (tgt >= vl ? 1 : 0);
      tp = A + (size_t)((k * 4 + vl) * SS + s) * DDIM;
      is_pos = true;
    } else if (tgt < 102) {
      int t2 = tgt - 3;
      if (t2 >= s) ++t2;
      tp = A + (size_t)((vl * 4 + vl) * SS + t2) * DDIM;
    } else {
      const int n = tgt - 102;
      tp = Nb + (size_t)((vl * SS + s) * NNEGS + n) * DDIM;
    }
    const ushort2 tt = *(const ushort2*)(tp + 2 * lane);
    float d = z0 * b2f(tt.x) + z1 * b2f(tt.y);
    #pragma unroll
    for (int m = 1; m < 64; m <<= 1) d += __shfl_xor(d, m);
    const float e = __expf(d * INV_TEMP);
    if (is_pos) pos_acc += e; else neg_acc += e;
  }

  __shared__ float sp[4], sn[4];
  if (lane == 0) { sp[wave] = pos_acc; sn[wave] = neg_acc; }
  __syncthreads();
  if (threadIdx.x == 0) {
    const float P  = sp[0] + sp[1] + sp[2] + sp[3];
    const float Ng = sn[0] + sn[1] + sn[2] + sn[3];
    atomicAdd(out, -logf(P / (P + Ng)) * (1.0f / 800.0f));
  }
}

extern "C" void kernel_launch(void* const* d_in, const int* in_sizes, int n_in,
                              void* d_out, int out_size, void* d_ws, size_t ws_size,
                              hipStream_t stream) {
  const float* emb_p = (const float*)d_in[0];
  const float* emb_c = (const float*)d_in[1];
  const float* W1    = (const float*)d_in[2];
  const float* b1    = (const float*)d_in[3];
  const float* W2    = (const float*)d_in[4];
  const float* b2    = (const float*)d_in[5];
  const void*  idx_p  = d_in[6];
  const void*  idx_c  = d_in[7];
  const void*  nidx_p = d_in[8];
  const void*  nidx_c = d_in[9];
  float* out = (float*)d_out;
  ushort_t* zrows = (ushort_t*)d_ws;
  ushort_t* wfrag = (ushort_t*)((char*)d_ws + ZROWS_BYTES);

  hipMemsetAsync(out, 0, sizeof(float), stream);
  wfrag_kernel<<<64, 64, 0, stream>>>(W1, W2, wfrag);
  proj_kernel<<<TOTAL_ROWS / BLK_ROWS, 256, 0, stream>>>(
      emb_p, emb_c, b1, b2, idx_p, idx_c, nidx_p, nidx_c, wfrag, zrows);
  loss_kernel<<<800, 256, 0, stream>>>(zrows, out);
}

// Round 3
// 41.906 us; speedup vs baseline: 3.0035x; 1.7567x over previous
//
#include <hip/hip_runtime.h>
#include <math.h>

#define NNODE 120000
#define DDIM  128
#define SS    100
#define NNEGS 50
#define ROWS_A 1600    // anchor/positive rows per type: slice(4) x idset(4) x 100
#define ROWS_N 20000   // cross-neg rows per type: vl(4) x s(100) x n(50)
#define TOTAL_ROWS 43200
#define BLK_ROWS 64
#define ZROWS_BYTES (TOTAL_ROWS * DDIM * 2)   // bf16 z rows
#define WFRAG_SHORTS 16384                    // per layer: kc(4) x ct(8) x lane(64) x 8
#define INV_TEMP 2.0f

typedef unsigned short ushort_t;
typedef __attribute__((ext_vector_type(8))) short bf16x8;
typedef __attribute__((ext_vector_type(8))) unsigned short u16x8;
typedef __attribute__((ext_vector_type(4))) float f32x4;

__device__ __forceinline__ ushort_t f2b(float f) {
  unsigned u = __builtin_bit_cast(unsigned, f);
  u += 0x7fffu + ((u >> 16) & 1u);           // RNE
  return (ushort_t)(u >> 16);
}
__device__ __forceinline__ float b2f(ushort_t h) {
  return __builtin_bit_cast(float, (unsigned)h << 16);
}
__device__ __forceinline__ bool idx_is64(const void* p) {
  const unsigned* q = (const unsigned*)p;
  return (q[1] | q[3] | q[5] | q[7]) == 0u;
}
__device__ __forceinline__ int ld_idx(const void* p, int i, bool is64) {
  return is64 ? (int)((const long long*)p)[i] : ((const int*)p)[i];
}

// ws z-row layout (bf16 rows of 128):
//   [0,1600)       A_p : slice(4) x idset(4) x s(100)
//   [1600,3200)    A_c
//   [3200,23200)   N_pc : vl(4) x s(100) x n(50)   (emb_c at neg_idx_p)
//   [23200,43200)  N_cp
__device__ __forceinline__ const float* row_src(
    int rid, bool is64,
    const float* emb_p, const float* emb_c,
    const void* idx_p, const void* idx_c,
    const void* nidx_p, const void* nidx_c)
{
  if (rid < 2 * ROWS_A) {
    const int typ = rid / ROWS_A;
    const int rr  = rid - typ * ROWS_A;
    const int slice = rr / 400;
    const int rem   = rr - slice * 400;          // idset*100 + s
    const int node  = ld_idx(typ ? idx_c : idx_p, rem, is64);
    return (typ ? emb_c : emb_p) + ((size_t)slice * NNODE + node) * DDIM;
  } else {
    const int r2  = rid - 2 * ROWS_A;
    const int typ = r2 / ROWS_N;
    const int rr  = r2 - typ * ROWS_N;
    const int slice = rr / (SS * NNEGS);
    const int rem   = rr - slice * (SS * NNEGS);
    const int node  = ld_idx(typ ? nidx_c : nidx_p, slice * (SS * NNEGS) + rem, is64);
    return (typ ? emb_p : emb_c) + ((size_t)slice * NNODE + node) * DDIM;
  }
}

// W -> B-fragment order (bf16): frag[layer][kc][ct][lane][e] =
//   W[kc*32 + 8*(lane>>4) + e][ct*16 + (lane&15)]
__global__ __launch_bounds__(64)
void wfrag_kernel(const float* __restrict__ W1, const float* __restrict__ W2,
                  ushort_t* __restrict__ wfrag, float* __restrict__ out)
{
  if (blockIdx.x == 0 && threadIdx.x == 0) out[0] = 0.f;   // fold memset node
  const int b = blockIdx.x;                 // 64 = layer(2) x kc(4) x ct(8)
  const int layer = b >> 5, kc = (b >> 3) & 3, ct = b & 7;
  const int l = threadIdx.x;
  const float* W = layer ? W2 : W1;
  ushort_t* dst = wfrag + layer * WFRAG_SHORTS + (size_t)((kc * 8 + ct) * 64 + l) * 8;
  const int col   = ct * 16 + (l & 15);
  const int krow0 = kc * 32 + ((l >> 4) << 3);
  #pragma unroll
  for (int e = 0; e < 8; ++e)
    dst[e] = f2b(W[(size_t)(krow0 + e) * DDIM + col]);
}

__global__ __launch_bounds__(256)
void proj_kernel(const float* __restrict__ emb_p, const float* __restrict__ emb_c,
                 const float* __restrict__ b1v, const float* __restrict__ b2v,
                 const void* __restrict__ idx_p, const void* __restrict__ idx_c,
                 const void* __restrict__ nidx_p, const void* __restrict__ nidx_c,
                 const ushort_t* __restrict__ wfrag,
                 ushort_t* __restrict__ zout)
{
  __shared__ __align__(16) ushort_t wlds[2 * WFRAG_SHORTS];   // W1+W2 frags, 64 KB
  __shared__ __align__(16) ushort_t hlds[BLK_ROWS * DDIM];    // 16 KB, wave-private slabs
  const int t = threadIdx.x, w = t >> 6, l = t & 63;
  const int g = l >> 4, li = l & 15;
  const bool is64 = idx_is64(idx_p);
  const int base = blockIdx.x * BLK_ROWS;
  const int r0 = w * 16;
  char* hb = (char*)hlds;

  // stage W1+W2 frags into LDS (coalesced, 64 KB)
  {
    const uint4* s4 = (const uint4*)wfrag;
    uint4* d4 = (uint4*)wlds;
    #pragma unroll
    for (int i = 0; i < 16; ++i) d4[t + 256 * i] = s4[t + 256 * i];
  }
  // gather this lane's row straight into A-fragment registers
  const float* src = row_src(base + r0 + li, is64,
                             emb_p, emb_c, idx_p, idx_c, nidx_p, nidx_c);
  bf16x8 afrag[4];
  #pragma unroll
  for (int kc = 0; kc < 4; ++kc) {
    const float4 xa = *(const float4*)(src + kc * 32 + g * 8);
    const float4 xb = *(const float4*)(src + kc * 32 + g * 8 + 4);
    bf16x8 af;
    af[0]=(short)f2b(xa.x); af[1]=(short)f2b(xa.y); af[2]=(short)f2b(xa.z); af[3]=(short)f2b(xa.w);
    af[4]=(short)f2b(xb.x); af[5]=(short)f2b(xb.y); af[6]=(short)f2b(xb.z); af[7]=(short)f2b(xb.w);
    afrag[kc] = af;
  }
  __syncthreads();                                   // weights visible

  f32x4 acc[8];
  // ---- layer 1: H = relu(X @ W1 + b1) ----
  #pragma unroll
  for (int ct = 0; ct < 8; ++ct) {
    const float bv = b1v[ct * 16 + li];
    acc[ct] = (f32x4){bv, bv, bv, bv};
  }
  #pragma unroll
  for (int kc = 0; kc < 4; ++kc)
    #pragma unroll
    for (int ct = 0; ct < 8; ++ct)
      acc[ct] = __builtin_amdgcn_mfma_f32_16x16x32_bf16(
          afrag[kc], *(const bf16x8*)&wlds[((kc * 8 + ct) * 64 + l) * 8], acc[ct], 0, 0, 0);

  // relu -> hlds (XOR-swizzled rows; slab is wave-private, DS in-order per wave)
  #pragma unroll
  for (int ct = 0; ct < 8; ++ct)
    #pragma unroll
    for (int rg = 0; rg < 4; ++rg) {
      const int row = r0 + 4 * g + rg;
      const int byte = row * 256 + (ct * 16 + li) * 2;
      *(ushort_t*)(hb + (byte ^ ((row & 7) << 4))) = f2b(fmaxf(acc[ct][rg], 0.f));
    }

  // ---- layer 2: Z = H @ W2 + b2 ----
  #pragma unroll
  for (int ct = 0; ct < 8; ++ct) {
    const float bv = b2v[ct * 16 + li];
    acc[ct] = (f32x4){bv, bv, bv, bv};
  }
  {
    const int row = r0 + li;
    #pragma unroll
    for (int kc = 0; kc < 4; ++kc) {
      const int byte = row * 256 + kc * 64 + g * 16;
      const bf16x8 hf = *(const bf16x8*)(hb + (byte ^ ((row & 7) << 4)));
      #pragma unroll
      for (int ct = 0; ct < 8; ++ct)
        acc[ct] = __builtin_amdgcn_mfma_f32_16x16x32_bf16(
            hf, *(const bf16x8*)&wlds[WFRAG_SHORTS + ((kc * 8 + ct) * 64 + l) * 8],
            acc[ct], 0, 0, 0);
    }
  }
  // ---- L2 norm (rows live across the 16-lane group) ----
  float sc[4];
  #pragma unroll
  for (int rg = 0; rg < 4; ++rg) {
    float ssq = 0.f;
    #pragma unroll
    for (int ct = 0; ct < 8; ++ct) ssq += acc[ct][rg] * acc[ct][rg];
    ssq += __shfl_xor(ssq, 1);
    ssq += __shfl_xor(ssq, 2);
    ssq += __shfl_xor(ssq, 4);
    ssq += __shfl_xor(ssq, 8);
    sc[rg] = 1.f / fmaxf(sqrtf(ssq), 1e-12f);
  }
  // normalized z (bf16) -> own slab, linear layout (H reads already issued)
  #pragma unroll
  for (int ct = 0; ct < 8; ++ct)
    #pragma unroll
    for (int rg = 0; rg < 4; ++rg)
      hlds[(r0 + 4 * g + rg) * DDIM + ct * 16 + li] = f2b(acc[ct][rg] * sc[rg]);
  // coalesced 4 KB copy-out of own slab (no barrier: wave-private)
  {
    const uint4* s4 = (const uint4*)&hlds[r0 * DDIM];
    uint4* d4 = (uint4*)(zout + (size_t)(base + r0) * DDIM);
    #pragma unroll
    for (int i = 0; i < 4; ++i) d4[l + 64 * i] = s4[l + 64 * i];
  }
}

// one target per lane: lane computes its full 128-dot, single reduce per wave
__global__ __launch_bounds__(192)
void loss_kernel(const ushort_t* __restrict__ zb, float* __restrict__ out)
{
  __shared__ __align__(16) float zf[DDIM];
  __shared__ float sp[3], sn[3];
  const int bid = blockIdx.x;            // type(2) x vl(4) x s(100)
  const int typ = bid / 400;
  const int rem = bid - typ * 400;
  const int vl  = rem / SS;
  const int s   = rem - vl * SS;
  const ushort_t* A  = zb + (size_t)(typ ? ROWS_A : 0) * DDIM;
  const ushort_t* Nb = zb + (size_t)(2 * ROWS_A + (typ ? ROWS_N : 0)) * DDIM;
  const ushort_t* zs = A + (size_t)((vl * 4 + vl) * SS + s) * DDIM;
  const int t = threadIdx.x, lane = t & 63, w = t >> 6;

  if (t < DDIM) zf[t] = b2f(zs[t]);
  __syncthreads();

  float e = 0.f;
  if (t < 152) {
    const ushort_t* tp;
    if (t < 3) {                                     // positives: other 3 slices
      const int k = t + (t >= vl ? 1 : 0);
      tp = A + (size_t)((k * 4 + vl) * SS + s) * DDIM;
    } else if (t < 102) {                            // within-negs, skip self
      int t2 = t - 3;
      if (t2 >= s) ++t2;
      tp = A + (size_t)((vl * 4 + vl) * SS + t2) * DDIM;
    } else {                                         // cross-negs
      tp = Nb + (size_t)((vl * SS + s) * NNEGS + (t - 102)) * DDIM;
    }
    float d0 = 0.f, d1 = 0.f, d2 = 0.f, d3 = 0.f;
    #pragma unroll
    for (int c = 0; c < 16; ++c) {
      const u16x8 tv = *(const u16x8*)(tp + c * 8);
      const float4 za = *(const float4*)&zf[c * 8];
      const float4 zc = *(const float4*)&zf[c * 8 + 4];
      d0 = fmaf(b2f(tv[0]), za.x, d0);
      d1 = fmaf(b2f(tv[1]), za.y, d1);
      d2 = fmaf(b2f(tv[2]), za.z, d2);
      d3 = fmaf(b2f(tv[3]), za.w, d3);
      d0 = fmaf(b2f(tv[4]), zc.x, d0);
      d1 = fmaf(b2f(tv[5]), zc.y, d1);
      d2 = fmaf(b2f(tv[6]), zc.z, d2);
      d3 = fmaf(b2f(tv[7]), zc.w, d3);
    }
    e = __expf(((d0 + d1) + (d2 + d3)) * INV_TEMP);
  }
  float pe = (t < 3) ? e : 0.f;
  float ne = (t < 3) ? 0.f : e;
  #pragma unroll
  for (int m = 1; m < 64; m <<= 1) {
    pe += __shfl_xor(pe, m);
    ne += __shfl_xor(ne, m);
  }
  if (lane == 0) { sp[w] = pe; sn[w] = ne; }
  __syncthreads();
  if (t == 0) {
    const float P  = sp[0] + sp[1] + sp[2];
    const float Ng = sn[0] + sn[1] + sn[2];
    atomicAdd(out, -logf(P / (P + Ng)) * (1.0f / 800.0f));
  }
}

extern "C" void kernel_launch(void* const* d_in, const int* in_sizes, int n_in,
                              void* d_out, int out_size, void* d_ws, size_t ws_size,
                              hipStream_t stream) {
  const float* emb_p = (const float*)d_in[0];
  const float* emb_c = (const float*)d_in[1];
  const float* W1    = (const float*)d_in[2];
  const float* b1    = (const float*)d_in[3];
  const float* W2    = (const float*)d_in[4];
  const float* b2    = (const float*)d_in[5];
  const void*  idx_p  = d_in[6];
  const void*  idx_c  = d_in[7];
  const void*  nidx_p = d_in[8];
  const void*  nidx_c = d_in[9];
  float* out = (float*)d_out;
  ushort_t* zrows = (ushort_t*)d_ws;
  ushort_t* wfrag = (ushort_t*)((char*)d_ws + ZROWS_BYTES);

  wfrag_kernel<<<64, 64, 0, stream>>>(W1, W2, wfrag, out);
  proj_kernel<<<TOTAL_ROWS / BLK_ROWS, 256, 0, stream>>>(
      emb_p, emb_c, b1, b2, idx_p, idx_c, nidx_p, nidx_c, wfrag, zrows);
  loss_kernel<<<800, 192, 0, stream>>>(zrows, out);
}

// Round 4
// 41.278 us; speedup vs baseline: 3.0493x; 1.0152x over previous
//
#include <hip/hip_runtime.h>
#include <math.h>

#define NNODE 120000
#define DDIM  128
#define SS    100
#define NNEGS 50
#define ROWS_A 1600    // anchor/positive rows per type: slice(4) x idset(4) x 100
#define ROWS_N 20000   // cross-neg rows per type: vl(4) x s(100) x n(50)
#define TOTAL_ROWS 43200
#define BLK_ROWS 128
#define GRID_ROWS 43264                      // 338 blocks x 128 (pad absorbs clamp dups)
#define ZPAD_BYTES (GRID_ROWS * DDIM * 2)
#define WFRAG_SHORTS 16384                   // per layer: kc(4) x ct(8) x lane(64) x 8
#define INV_TEMP 2.0f

typedef unsigned short ushort_t;
typedef __attribute__((ext_vector_type(8))) short bf16x8;
typedef __attribute__((ext_vector_type(8))) unsigned short u16x8;
typedef __attribute__((ext_vector_type(4))) float f32x4;

__device__ __forceinline__ ushort_t f2b(float f) {
  unsigned u = __builtin_bit_cast(unsigned, f);
  u += 0x7fffu + ((u >> 16) & 1u);           // RNE
  return (ushort_t)(u >> 16);
}
__device__ __forceinline__ float b2f(ushort_t h) {
  return __builtin_bit_cast(float, (unsigned)h << 16);
}
__device__ __forceinline__ bool idx_is64(const void* p) {
  const unsigned* q = (const unsigned*)p;
  return (q[1] | q[3] | q[5] | q[7]) == 0u;
}
__device__ __forceinline__ int ld_idx(const void* p, int i, bool is64) {
  return is64 ? (int)((const long long*)p)[i] : ((const int*)p)[i];
}

// ws z-row layout (bf16 rows of 128):
//   [0,1600)       A_p : slice(4) x idset(4) x s(100)
//   [1600,3200)    A_c
//   [3200,23200)   N_pc : vl(4) x s(100) x n(50)   (emb_c at neg_idx_p)
//   [23200,43200)  N_cp          [43200,43264) pad
__device__ __forceinline__ const float* row_src(
    int rid, bool is64,
    const float* emb_p, const float* emb_c,
    const void* idx_p, const void* idx_c,
    const void* nidx_p, const void* nidx_c)
{
  if (rid < 2 * ROWS_A) {
    const int typ = rid / ROWS_A;
    const int rr  = rid - typ * ROWS_A;
    const int slice = rr / 400;
    const int rem   = rr - slice * 400;          // idset*100 + s
    const int node  = ld_idx(typ ? idx_c : idx_p, rem, is64);
    return (typ ? emb_c : emb_p) + ((size_t)slice * NNODE + node) * DDIM;
  } else {
    const int r2  = rid - 2 * ROWS_A;
    const int typ = r2 / ROWS_N;
    const int rr  = r2 - typ * ROWS_N;
    const int slice = rr / (SS * NNEGS);
    const int rem   = rr - slice * (SS * NNEGS);
    const int node  = ld_idx(typ ? nidx_c : nidx_p, slice * (SS * NNEGS) + rem, is64);
    return (typ ? emb_p : emb_c) + ((size_t)slice * NNODE + node) * DDIM;
  }
}

// W -> B-fragment order (bf16): frag[layer][kc][ct][lane][e] =
//   W[kc*32 + 8*(lane>>4) + e][ct*16 + (lane&15)]
__global__ __launch_bounds__(64)
void wfrag_kernel(const float* __restrict__ W1, const float* __restrict__ W2,
                  ushort_t* __restrict__ wfrag, float* __restrict__ out)
{
  if (blockIdx.x == 0 && threadIdx.x == 0) out[0] = 0.f;   // fold memset node
  const int b = blockIdx.x;                 // 64 = layer(2) x kc(4) x ct(8)
  const int layer = b >> 5, kc = (b >> 3) & 3, ct = b & 7;
  const int l = threadIdx.x;
  const float* W = layer ? W2 : W1;
  ushort_t* dst = wfrag + layer * WFRAG_SHORTS + (size_t)((kc * 8 + ct) * 64 + l) * 8;
  const int col   = ct * 16 + (l & 15);
  const int krow0 = kc * 32 + ((l >> 4) << 3);
  #pragma unroll
  for (int e = 0; e < 8; ++e)
    dst[e] = f2b(W[(size_t)(krow0 + e) * DDIM + col]);
}

__global__ __launch_bounds__(512)
void proj_kernel(const float* __restrict__ emb_p, const float* __restrict__ emb_c,
                 const float* __restrict__ b1v, const float* __restrict__ b2v,
                 const void* __restrict__ idx_p, const void* __restrict__ idx_c,
                 const void* __restrict__ nidx_p, const void* __restrict__ nidx_c,
                 const ushort_t* __restrict__ wfrag,
                 ushort_t* __restrict__ zout)
{
  __shared__ __align__(16) ushort_t wlds[WFRAG_SHORTS];       // 32 KB, one layer at a time
  __shared__ __align__(16) ushort_t hlds[BLK_ROWS * DDIM];    // 32 KB, wave-private 16-row slabs
  const int t = threadIdx.x, w = t >> 6, l = t & 63;
  const int g = l >> 4, li = l & 15;
  const bool is64 = idx_is64(idx_p);
  const int base = blockIdx.x * BLK_ROWS;
  const int r0 = w * 16;
  char* hb = (char*)hlds;

  // ---- issue this lane's row gather FIRST (HBM latency hides under staging) ----
  int rid = base + r0 + li;
  if (rid > TOTAL_ROWS - 1) rid = TOTAL_ROWS - 1;
  const float* src = row_src(rid, is64, emb_p, emb_c, idx_p, idx_c, nidx_p, nidx_c);
  float4 xr[8];
  #pragma unroll
  for (int kc = 0; kc < 4; ++kc) {
    xr[2 * kc]     = *(const float4*)(src + kc * 32 + g * 8);
    xr[2 * kc + 1] = *(const float4*)(src + kc * 32 + g * 8 + 4);
  }
  // ---- stage W1 frags (32 KB from L2) ----
  {
    const uint4* s4 = (const uint4*)wfrag;
    uint4* d4 = (uint4*)wlds;
    #pragma unroll
    for (int i = 0; i < 4; ++i) d4[t + 512 * i] = s4[t + 512 * i];
  }
  // convert gathered row to A fragments
  bf16x8 afrag[4];
  #pragma unroll
  for (int kc = 0; kc < 4; ++kc) {
    const float4 xa = xr[2 * kc], xb = xr[2 * kc + 1];
    bf16x8 af;
    af[0]=(short)f2b(xa.x); af[1]=(short)f2b(xa.y); af[2]=(short)f2b(xa.z); af[3]=(short)f2b(xa.w);
    af[4]=(short)f2b(xb.x); af[5]=(short)f2b(xb.y); af[6]=(short)f2b(xb.z); af[7]=(short)f2b(xb.w);
    afrag[kc] = af;
  }
  __syncthreads();                                   // W1 visible

  f32x4 acc[8];
  // ---- layer 1: H = relu(X @ W1 + b1) ----
  #pragma unroll
  for (int ct = 0; ct < 8; ++ct) {
    const float bv = b1v[ct * 16 + li];
    acc[ct] = (f32x4){bv, bv, bv, bv};
  }
  #pragma unroll
  for (int kc = 0; kc < 4; ++kc)
    #pragma unroll
    for (int ct = 0; ct < 8; ++ct)
      acc[ct] = __builtin_amdgcn_mfma_f32_16x16x32_bf16(
          afrag[kc], *(const bf16x8*)&wlds[((kc * 8 + ct) * 64 + l) * 8], acc[ct], 0, 0, 0);

  // relu -> hlds (XOR-swizzled rows; slab is wave-private, DS in-order per wave)
  #pragma unroll
  for (int ct = 0; ct < 8; ++ct)
    #pragma unroll
    for (int rg = 0; rg < 4; ++rg) {
      const int row = r0 + 4 * g + rg;
      const int byte = row * 256 + (ct * 16 + li) * 2;
      *(ushort_t*)(hb + (byte ^ ((row & 7) << 4))) = f2b(fmaxf(acc[ct][rg], 0.f));
    }
  __syncthreads();                                   // all waves done reading W1
  // ---- stage W2 frags over W1 ----
  {
    const uint4* s4 = (const uint4*)(wfrag + WFRAG_SHORTS);
    uint4* d4 = (uint4*)wlds;
    #pragma unroll
    for (int i = 0; i < 4; ++i) d4[t + 512 * i] = s4[t + 512 * i];
  }
  __syncthreads();                                   // W2 visible

  // ---- layer 2: Z = H @ W2 + b2 ----
  #pragma unroll
  for (int ct = 0; ct < 8; ++ct) {
    const float bv = b2v[ct * 16 + li];
    acc[ct] = (f32x4){bv, bv, bv, bv};
  }
  {
    const int row = r0 + li;
    #pragma unroll
    for (int kc = 0; kc < 4; ++kc) {
      const int byte = row * 256 + kc * 64 + g * 16;
      const bf16x8 hf = *(const bf16x8*)(hb + (byte ^ ((row & 7) << 4)));
      #pragma unroll
      for (int ct = 0; ct < 8; ++ct)
        acc[ct] = __builtin_amdgcn_mfma_f32_16x16x32_bf16(
            hf, *(const bf16x8*)&wlds[((kc * 8 + ct) * 64 + l) * 8], acc[ct], 0, 0, 0);
    }
  }
  // ---- L2 norm (rows live across the 16-lane group) ----
  float sc[4];
  #pragma unroll
  for (int rg = 0; rg < 4; ++rg) {
    float ssq = 0.f;
    #pragma unroll
    for (int ct = 0; ct < 8; ++ct) ssq += acc[ct][rg] * acc[ct][rg];
    ssq += __shfl_xor(ssq, 1);
    ssq += __shfl_xor(ssq, 2);
    ssq += __shfl_xor(ssq, 4);
    ssq += __shfl_xor(ssq, 8);
    sc[rg] = 1.f / fmaxf(sqrtf(ssq), 1e-12f);
  }
  // normalized z (bf16) -> own slab, linear layout (own H reads already done; in-order DS)
  #pragma unroll
  for (int ct = 0; ct < 8; ++ct)
    #pragma unroll
    for (int rg = 0; rg < 4; ++rg)
      hlds[(r0 + 4 * g + rg) * DDIM + ct * 16 + li] = f2b(acc[ct][rg] * sc[rg]);
  // coalesced 4 KB copy-out of own slab (no barrier: wave-private)
  {
    const uint4* s4 = (const uint4*)&hlds[r0 * DDIM];
    uint4* d4 = (uint4*)(zout + (size_t)(base + r0) * DDIM);
    #pragma unroll
    for (int i = 0; i < 4; ++i) d4[l + 64 * i] = s4[l + 64 * i];
  }
}

// one target per lane: lane computes its full 128-dot, single reduce per wave
__global__ __launch_bounds__(192)
void loss_kernel(const ushort_t* __restrict__ zb, float* __restrict__ out)
{
  __shared__ __align__(16) float zf[DDIM];
  __shared__ float sp[3], sn[3];
  const int bid = blockIdx.x;            // type(2) x vl(4) x s(100)
  const int typ = bid / 400;
  const int rem = bid - typ * 400;
  const int vl  = rem / SS;
  const int s   = rem - vl * SS;
  const ushort_t* A  = zb + (size_t)(typ ? ROWS_A : 0) * DDIM;
  const ushort_t* Nb = zb + (size_t)(2 * ROWS_A + (typ ? ROWS_N : 0)) * DDIM;
  const ushort_t* zs = A + (size_t)((vl * 4 + vl) * SS + s) * DDIM;
  const int t = threadIdx.x, lane = t & 63, w = t >> 6;

  if (t < DDIM) zf[t] = b2f(zs[t]);
  __syncthreads();

  float e = 0.f;
  if (t < 152) {
    const ushort_t* tp;
    if (t < 3) {                                     // positives: other 3 slices
      const int k = t + (t >= vl ? 1 : 0);
      tp = A + (size_t)((k * 4 + vl) * SS + s) * DDIM;
    } else if (t < 102) {                            // within-negs, skip self
      int t2 = t - 3;
      if (t2 >= s) ++t2;
      tp = A + (size_t)((vl * 4 + vl) * SS + t2) * DDIM;
    } else {                                         // cross-negs
      tp = Nb + (size_t)((vl * SS + s) * NNEGS + (t - 102)) * DDIM;
    }
    float d0 = 0.f, d1 = 0.f, d2 = 0.f, d3 = 0.f;
    #pragma unroll
    for (int c = 0; c < 16; ++c) {
      const u16x8 tv = *(const u16x8*)(tp + c * 8);
      const float4 za = *(const float4*)&zf[c * 8];
      const float4 zc = *(const float4*)&zf[c * 8 + 4];
      d0 = fmaf(b2f(tv[0]), za.x, d0);
      d1 = fmaf(b2f(tv[1]), za.y, d1);
      d2 = fmaf(b2f(tv[2]), za.z, d2);
      d3 = fmaf(b2f(tv[3]), za.w, d3);
      d0 = fmaf(b2f(tv[4]), zc.x, d0);
      d1 = fmaf(b2f(tv[5]), zc.y, d1);
      d2 = fmaf(b2f(tv[6]), zc.z, d2);
      d3 = fmaf(b2f(tv[7]), zc.w, d3);
    }
    e = __expf(((d0 + d1) + (d2 + d3)) * INV_TEMP);
  }
  float pe = (t < 3) ? e : 0.f;
  float ne = (t < 3) ? 0.f : e;
  #pragma unroll
  for (int m = 1; m < 64; m <<= 1) {
    pe += __shfl_xor(pe, m);
    ne += __shfl_xor(ne, m);
  }
  if (lane == 0) { sp[w] = pe; sn[w] = ne; }
  __syncthreads();
  if (t == 0) {
    const float P  = sp[0] + sp[1] + sp[2];
    const float Ng = sn[0] + sn[1] + sn[2];
    atomicAdd(out, -logf(P / (P + Ng)) * (1.0f / 800.0f));
  }
}

extern "C" void kernel_launch(void* const* d_in, const int* in_sizes, int n_in,
                              void* d_out, int out_size, void* d_ws, size_t ws_size,
                              hipStream_t stream) {
  const float* emb_p = (const float*)d_in[0];
  const float* emb_c = (const float*)d_in[1];
  const float* W1    = (const float*)d_in[2];
  const float* b1    = (const float*)d_in[3];
  const float* W2    = (const float*)d_in[4];
  const float* b2    = (const float*)d_in[5];
  const void*  idx_p  = d_in[6];
  const void*  idx_c  = d_in[7];
  const void*  nidx_p = d_in[8];
  const void*  nidx_c = d_in[9];
  float* out = (float*)d_out;
  ushort_t* zrows = (ushort_t*)d_ws;
  ushort_t* wfrag = (ushort_t*)((char*)d_ws + ZPAD_BYTES);

  wfrag_kernel<<<64, 64, 0, stream>>>(W1, W2, wfrag, out);
  proj_kernel<<<GRID_ROWS / BLK_ROWS, 512, 0, stream>>>(
      emb_p, emb_c, b1, b2, idx_p, idx_c, nidx_p, nidx_c, wfrag, zrows);
  loss_kernel<<<800, 192, 0, stream>>>(zrows, out);
}